// Round 1
// baseline (1531.067 us; speedup 1.0000x reference)
//
#include <hip/hip_runtime.h>

// Problem constants (setup_inputs): B=2, C=128, H=800, W=640, N=10000, O=18 outputs (9 neighbors x 2)
constexpr int BB = 2;
constexpr int CC = 128;
constexpr int HH = 800;
constexpr int WW = 640;
constexpr int NN = 10000;
constexpr int OO = 18;

// Faithful F.grid_sample(mode='bilinear', padding_mode='border', align_corners=True)
// for one channel plane `base` (H*W floats, row stride W).
__device__ __forceinline__ float bilin_sample(const float* __restrict__ base,
                                              float vx, float vy) {
    float gx = (vx + 1.0f) * 0.5f * (float)(WW - 1);
    float gy = (vy + 1.0f) * 0.5f * (float)(HH - 1);
    gx = fminf(fmaxf(gx, 0.0f), (float)(WW - 1));
    gy = fminf(fmaxf(gy, 0.0f), (float)(HH - 1));
    float x0f = floorf(gx);
    float y0f = floorf(gy);
    int x0 = (int)x0f;
    int y0 = (int)y0f;
    int x1 = min(x0 + 1, WW - 1);
    int y1 = min(y0 + 1, HH - 1);
    float wx1 = gx - x0f;
    float wy1 = gy - y0f;
    float wx0 = 1.0f - wx1;
    float wy0 = 1.0f - wy1;
    const float* r0 = base + (size_t)y0 * WW;
    const float* r1 = base + (size_t)y1 * WW;
    float v00 = r0[x0];
    float v01 = r0[x1];
    float v10 = r1[x0];
    float v11 = r1[x1];
    return (v00 * wx0 + v01 * wx1) * wy0 + (v10 * wx0 + v11 * wx1) * wy1;
}

__global__ void __launch_bounds__(CC)
lns_kernel(const float* __restrict__ img,     // (B, C, H, W)
           const float* __restrict__ verts,   // (B, N, 2)
           const float* __restrict__ conv_w,  // (18, C)
           const float* __restrict__ conv_b,  // (18,)
           float* __restrict__ out) {         // (B, N, C)
    const int p = blockIdx.x;         // point index in [0, B*N)
    const int b = p / NN;
    const int n = p - b * NN;
    const int c = threadIdx.x;        // channel

    __shared__ float s_feat[CC];
    __shared__ float s_delta[OO];

    const float vx = verts[((size_t)p) * 2 + 0];
    const float vy = verts[((size_t)p) * 2 + 1];

    const float* base = img + ((size_t)(b * CC + c)) * (size_t)(HH * WW);

    // Phase A: center sample (this is also neighbor j=0, since delta[0] := 0)
    const float fc = bilin_sample(base, vx, vy);
    s_feat[c] = fc;
    __syncthreads();

    // Phase B: delta = conv_w @ feats + conv_b   (18 outputs)
    if (c < OO) {
        float acc = conv_b[c];
        const float* wrow = conv_w + c * CC;
        #pragma unroll 8
        for (int k = 0; k < CC; ++k) acc += wrow[k] * s_feat[k];
        s_delta[c] = acc;
    }
    __syncthreads();

    // Phase C: 8 remaining neighbor samples + mean
    float acc = fc;   // neighbor 0 contributes the center sample
    #pragma unroll
    for (int j = 1; j < 9; ++j) {
        const float nx = vx + s_delta[2 * j + 0];
        const float ny = vy + s_delta[2 * j + 1];
        acc += bilin_sample(base, nx, ny);
    }
    out[((size_t)p) * CC + c] = acc * (1.0f / 9.0f);
}

extern "C" void kernel_launch(void* const* d_in, const int* in_sizes, int n_in,
                              void* d_out, int out_size, void* d_ws, size_t ws_size,
                              hipStream_t stream) {
    const float* img    = (const float*)d_in[0];
    const float* verts  = (const float*)d_in[1];
    const float* conv_w = (const float*)d_in[2];
    const float* conv_b = (const float*)d_in[3];
    float* out = (float*)d_out;

    dim3 grid(BB * NN);
    dim3 block(CC);
    lns_kernel<<<grid, block, 0, stream>>>(img, verts, conv_w, conv_b, out);
}

// Round 2
// 1279.820 us; speedup vs baseline: 1.1963x; 1.1963x over previous
//
#include <hip/hip_runtime.h>

// Problem constants: B=2, C=128, H=800, W=640, N=10000, 18 conv outputs (9 neighbors x 2)
constexpr int BB = 2;
constexpr int CC = 128;
constexpr int HH = 800;
constexpr int WW = 640;
constexpr int NN = 10000;
constexpr int OO = 18;
constexpr int NP = BB * NN;      // 20000 points
constexpr int S2 = NP * 8;       // 160000 neighbor samples (j=1..8; j=0 handled in K1)
constexpr int BAND_SHIFT = 2;    // 4-row bands
constexpr int NB = (HH + (1 << BAND_SHIFT) - 1) >> BAND_SHIFT;  // 200 bands
constexpr size_t HWsz = (size_t)HH * WW;

// Workspace layout (bytes)
constexpr size_t WS_COORDS = 0;                                   // float2[S2]
constexpr size_t WS_SGX    = WS_COORDS + sizeof(float) * 2 * S2;  // float[S2]
constexpr size_t WS_SGY    = WS_SGX + sizeof(float) * S2;         // float[S2]
constexpr size_t WS_SID    = WS_SGY + sizeof(float) * S2;         // uint[S2]
constexpr size_t WS_HIST   = WS_SID + sizeof(unsigned) * S2;      // uint[256]
constexpr size_t WS_CUR    = WS_HIST + sizeof(unsigned) * 256;    // uint[256]
constexpr size_t WS_NEEDED = WS_CUR + sizeof(unsigned) * 256;

// Bilinear sample of one channel plane at already-clamped pixel coords.
__device__ __forceinline__ float bilin_px(const float* __restrict__ base,
                                          float gx, float gy) {
    float x0f = floorf(gx);
    float y0f = floorf(gy);
    int x0 = (int)x0f;
    int y0 = (int)y0f;
    int x1 = min(x0 + 1, WW - 1);
    int y1 = min(y0 + 1, HH - 1);
    float wx1 = gx - x0f;
    float wy1 = gy - y0f;
    float wx0 = 1.0f - wx1;
    float wy0 = 1.0f - wy1;
    const float* r0 = base + (size_t)y0 * WW;
    const float* r1 = base + (size_t)y1 * WW;
    return (r0[x0] * wx0 + r0[x1] * wx1) * wy0 +
           (r1[x0] * wx0 + r1[x1] * wx1) * wy1;
}

__device__ __forceinline__ float to_px_x(float v) {
    float g = (v + 1.0f) * 0.5f * (float)(WW - 1);
    return fminf(fmaxf(g, 0.0f), (float)(WW - 1));
}
__device__ __forceinline__ float to_px_y(float v) {
    float g = (v + 1.0f) * 0.5f * (float)(HH - 1);
    return fminf(fmaxf(g, 0.0f), (float)(HH - 1));
}

// K1: center sample -> out/9, matvec -> deltas, emit 8 neighbor coords + band histogram.
__global__ void __launch_bounds__(CC)
k1_center(const float* __restrict__ img, const float* __restrict__ verts,
          const float* __restrict__ conv_w, const float* __restrict__ conv_b,
          float* __restrict__ out, float2* __restrict__ coords,
          unsigned* __restrict__ hist) {
    const int p = blockIdx.x;
    const int b = p / NN;
    const int c = threadIdx.x;

    __shared__ float s_feat[CC];
    __shared__ float s_delta[OO];

    const float vx = verts[(size_t)p * 2 + 0];
    const float vy = verts[(size_t)p * 2 + 1];
    const float gx = to_px_x(vx);
    const float gy = to_px_y(vy);

    const float* base = img + ((size_t)(b * CC + c)) * HWsz;
    const float fc = bilin_px(base, gx, gy);
    s_feat[c] = fc;
    __syncthreads();

    if (c < OO) {
        float acc = conv_b[c];
        const float* wrow = conv_w + c * CC;
        #pragma unroll 8
        for (int k = 0; k < CC; ++k) acc += wrow[k] * s_feat[k];
        s_delta[c] = acc;
    }
    __syncthreads();

    // j=0 neighbor == center (delta forced to 0): write its mean contribution now.
    out[(size_t)p * CC + c] = fc * (1.0f / 9.0f);

    if (c >= 1 && c < 9) {   // j = c in [1,8]
        const float nx = vx + s_delta[2 * c + 0];
        const float ny = vy + s_delta[2 * c + 1];
        const float ggx = to_px_x(nx);
        const float ggy = to_px_y(ny);
        const int idx = p * 8 + (c - 1);
        coords[idx] = make_float2(ggx, ggy);
        atomicAdd(&hist[((int)ggy) >> BAND_SHIFT], 1u);
    }
}

// K2: serial exclusive prefix sum over NB band counters -> cursor.
__global__ void k2_scan(const unsigned* __restrict__ hist,
                        unsigned* __restrict__ cursor) {
    if (threadIdx.x == 0 && blockIdx.x == 0) {
        unsigned acc = 0;
        for (int i = 0; i < NB; ++i) {
            cursor[i] = acc;
            acc += hist[i];
        }
    }
}

// K3: scatter samples into band-sorted order.
__global__ void __launch_bounds__(256)
k3_scatter(const float2* __restrict__ coords, unsigned* __restrict__ cursor,
           float* __restrict__ sgx, float* __restrict__ sgy,
           unsigned* __restrict__ sid) {
    const int i = blockIdx.x * 256 + threadIdx.x;
    if (i < S2) {
        const float2 cd = coords[i];
        const int band = ((int)cd.y) >> BAND_SHIFT;
        const unsigned pos = atomicAdd(&cursor[band], 1u);
        sgx[pos] = cd.x;
        sgy[pos] = cd.y;
        sid[pos] = (unsigned)(i >> 3);   // point index p = i/8
    }
}

// K4: one block per sorted sample; 128 channels; accumulate into out.
__global__ void __launch_bounds__(CC)
k4_sample(const float* __restrict__ img, const float* __restrict__ sgx,
          const float* __restrict__ sgy, const unsigned* __restrict__ sid,
          float* __restrict__ out) {
    const int r = blockIdx.x;
    const int c = threadIdx.x;
    const float gx = sgx[r];
    const float gy = sgy[r];
    const unsigned p = sid[r];
    const int b = (p >= (unsigned)NN) ? 1 : 0;

    const float* base = img + ((size_t)(b * CC + c)) * HWsz;
    const float v = bilin_px(base, gx, gy);
    atomicAdd(&out[(size_t)p * CC + c], v * (1.0f / 9.0f));
}

// Fallback: round-1 monolithic kernel (used only if ws is too small).
__global__ void __launch_bounds__(CC)
lns_kernel(const float* __restrict__ img, const float* __restrict__ verts,
           const float* __restrict__ conv_w, const float* __restrict__ conv_b,
           float* __restrict__ out) {
    const int p = blockIdx.x;
    const int b = p / NN;
    const int c = threadIdx.x;

    __shared__ float s_feat[CC];
    __shared__ float s_delta[OO];

    const float vx = verts[(size_t)p * 2 + 0];
    const float vy = verts[(size_t)p * 2 + 1];
    const float* base = img + ((size_t)(b * CC + c)) * HWsz;

    const float fc = bilin_px(base, to_px_x(vx), to_px_y(vy));
    s_feat[c] = fc;
    __syncthreads();

    if (c < OO) {
        float acc = conv_b[c];
        const float* wrow = conv_w + c * CC;
        #pragma unroll 8
        for (int k = 0; k < CC; ++k) acc += wrow[k] * s_feat[k];
        s_delta[c] = acc;
    }
    __syncthreads();

    float acc = fc;
    #pragma unroll
    for (int j = 1; j < 9; ++j) {
        const float nx = vx + s_delta[2 * j + 0];
        const float ny = vy + s_delta[2 * j + 1];
        acc += bilin_px(base, to_px_x(nx), to_px_y(ny));
    }
    out[(size_t)p * CC + c] = acc * (1.0f / 9.0f);
}

extern "C" void kernel_launch(void* const* d_in, const int* in_sizes, int n_in,
                              void* d_out, int out_size, void* d_ws, size_t ws_size,
                              hipStream_t stream) {
    const float* img    = (const float*)d_in[0];
    const float* verts  = (const float*)d_in[1];
    const float* conv_w = (const float*)d_in[2];
    const float* conv_b = (const float*)d_in[3];
    float* out = (float*)d_out;

    if (ws_size < WS_NEEDED) {
        // Not enough scratch for the sorted path — safe fallback.
        lns_kernel<<<dim3(NP), dim3(CC), 0, stream>>>(img, verts, conv_w, conv_b, out);
        return;
    }

    char* w = (char*)d_ws;
    float2*   coords = (float2*)(w + WS_COORDS);
    float*    sgx    = (float*)(w + WS_SGX);
    float*    sgy    = (float*)(w + WS_SGY);
    unsigned* sid    = (unsigned*)(w + WS_SID);
    unsigned* hist   = (unsigned*)(w + WS_HIST);
    unsigned* cursor = (unsigned*)(w + WS_CUR);

    hipMemsetAsync(hist, 0, sizeof(unsigned) * 256, stream);

    k1_center<<<dim3(NP), dim3(CC), 0, stream>>>(img, verts, conv_w, conv_b,
                                                 out, coords, hist);
    k2_scan<<<dim3(1), dim3(64), 0, stream>>>(hist, cursor);
    k3_scatter<<<dim3((S2 + 255) / 256), dim3(256), 0, stream>>>(coords, cursor,
                                                                 sgx, sgy, sid);
    k4_sample<<<dim3(S2), dim3(CC), 0, stream>>>(img, sgx, sgy, sid, out);
}

// Round 3
// 841.016 us; speedup vs baseline: 1.8205x; 1.5218x over previous
//
#include <hip/hip_runtime.h>

// Problem constants: B=2, C=128, H=800, W=640, N=10000, 18 conv outputs (9 neighbors x 2)
constexpr int BB = 2;
constexpr int CC = 128;
constexpr int HH = 800;
constexpr int WW = 640;
constexpr int NN = 10000;
constexpr int OO = 18;
constexpr int NP = BB * NN;      // 20000 points
constexpr size_t HWsz = (size_t)HH * WW;              // 512000 pixels
constexpr int TP = 64;                                 // pixels per transpose tile
constexpr int TILES_PER_B = (int)(HWsz / TP);          // 8000
constexpr size_t WS_TRANS_BYTES = (size_t)BB * HWsz * CC * sizeof(float);  // 524,288,000

// ---- legacy banded-path workspace (fallback #1) ----
constexpr int S2 = NP * 8;
constexpr int BAND_SHIFT = 2;
constexpr int NB = (HH + (1 << BAND_SHIFT) - 1) >> BAND_SHIFT;
constexpr size_t WS_COORDS = 0;
constexpr size_t WS_SGX    = WS_COORDS + sizeof(float) * 2 * S2;
constexpr size_t WS_SGY    = WS_SGX + sizeof(float) * S2;
constexpr size_t WS_SID    = WS_SGY + sizeof(float) * S2;
constexpr size_t WS_HIST   = WS_SID + sizeof(unsigned) * S2;
constexpr size_t WS_CUR    = WS_HIST + sizeof(unsigned) * 256;
constexpr size_t WS_BAND_NEEDED = WS_CUR + sizeof(unsigned) * 256;

__device__ __forceinline__ float to_px_x(float v) {
    float g = (v + 1.0f) * 0.5f * (float)(WW - 1);
    return fminf(fmaxf(g, 0.0f), (float)(WW - 1));
}
__device__ __forceinline__ float to_px_y(float v) {
    float g = (v + 1.0f) * 0.5f * (float)(HH - 1);
    return fminf(fmaxf(g, 0.0f), (float)(HH - 1));
}

// ===================== Fast path: transpose + fused coalesced gather =====================

// kT: (B,C,H,W) -> (B,HW,C). Tile = 64 pixels x 128 channels, LDS-mediated.
__global__ void __launch_bounds__(256)
kT(const float* __restrict__ img, float* __restrict__ trans) {
    __shared__ float lds[CC][TP + 1];   // pad 65: 2-way max bank aliasing both phases
    const int tile = blockIdx.x;
    const int b = tile / TILES_PER_B;
    const int pix0 = (tile - b * TILES_PER_B) * TP;

    // Read phase: 8 rounds x (16 channels x 64 pixels via float4)
    const int cg   = threadIdx.x & 15;   // pixel group (4 px each)
    const int crow = threadIdx.x >> 4;   // 0..15
    #pragma unroll
    for (int r = 0; r < 8; ++r) {
        const int c = r * 16 + crow;
        const float4 v = *(const float4*)(img + ((size_t)(b * CC + c)) * HWsz + pix0 + 4 * cg);
        lds[c][4 * cg + 0] = v.x;
        lds[c][4 * cg + 1] = v.y;
        lds[c][4 * cg + 2] = v.z;
        lds[c][4 * cg + 3] = v.w;
    }
    __syncthreads();

    // Write phase: 32 rounds x (2 pixels x 128 channels), fully coalesced 512 B/pixel.
    const int c2    = threadIdx.x & 127;
    const int phalf = threadIdx.x >> 7;  // 0..1
    float* tbase = trans + ((size_t)b * HWsz + pix0) * CC;
    #pragma unroll 4
    for (int w = 0; w < 32; ++w) {
        const int pix = w * 2 + phalf;
        tbase[(size_t)pix * CC + c2] = lds[c2][pix];
    }
}

// Bilinear from NHWC-transposed image; taps are 128-float contiguous rows.
__device__ __forceinline__ float bilin_nhwc(const float* __restrict__ tb,
                                            float gx, float gy, int c) {
    float x0f = floorf(gx);
    float y0f = floorf(gy);
    int x0 = (int)x0f;
    int y0 = (int)y0f;
    int x1 = min(x0 + 1, WW - 1);
    int y1 = min(y0 + 1, HH - 1);
    float wx1 = gx - x0f;
    float wy1 = gy - y0f;
    float wx0 = 1.0f - wx1;
    float wy0 = 1.0f - wy1;
    const float* r0 = tb + (size_t)y0 * WW * CC;
    const float* r1 = tb + (size_t)y1 * WW * CC;
    float v00 = r0[(size_t)x0 * CC + c];
    float v01 = r0[(size_t)x1 * CC + c];
    float v10 = r1[(size_t)x0 * CC + c];
    float v11 = r1[(size_t)x1 * CC + c];
    return (v00 * wx0 + v01 * wx1) * wy0 + (v10 * wx0 + v11 * wx1) * wy1;
}

// kG: one block per point; center sample -> matvec -> 8 neighbors -> mean. All coalesced.
__global__ void __launch_bounds__(CC)
kG(const float* __restrict__ trans, const float* __restrict__ verts,
   const float* __restrict__ conv_w, const float* __restrict__ conv_b,
   float* __restrict__ out) {
    const int p = blockIdx.x;
    const int b = p / NN;
    const int c = threadIdx.x;

    __shared__ float s_feat[CC];
    __shared__ float s_delta[OO];

    const float vx = verts[(size_t)p * 2 + 0];
    const float vy = verts[(size_t)p * 2 + 1];
    const float* tb = trans + (size_t)b * HWsz * CC;

    const float fc = bilin_nhwc(tb, to_px_x(vx), to_px_y(vy), c);
    s_feat[c] = fc;
    __syncthreads();

    if (c < OO) {
        float acc = conv_b[c];
        const float* wrow = conv_w + c * CC;
        #pragma unroll 8
        for (int k = 0; k < CC; ++k) acc += wrow[k] * s_feat[k];
        s_delta[c] = acc;
    }
    __syncthreads();

    float acc = fc;
    #pragma unroll
    for (int j = 1; j < 9; ++j) {
        const float nx = vx + s_delta[2 * j + 0];
        const float ny = vy + s_delta[2 * j + 1];
        acc += bilin_nhwc(tb, to_px_x(nx), to_px_y(ny), c);
    }
    out[(size_t)p * CC + c] = acc * (1.0f / 9.0f);
}

// ===================== Fallback #1: R2 banded path =====================

__device__ __forceinline__ float bilin_px(const float* __restrict__ base,
                                          float gx, float gy) {
    float x0f = floorf(gx);
    float y0f = floorf(gy);
    int x0 = (int)x0f;
    int y0 = (int)y0f;
    int x1 = min(x0 + 1, WW - 1);
    int y1 = min(y0 + 1, HH - 1);
    float wx1 = gx - x0f;
    float wy1 = gy - y0f;
    float wx0 = 1.0f - wx1;
    float wy0 = 1.0f - wy1;
    const float* r0 = base + (size_t)y0 * WW;
    const float* r1 = base + (size_t)y1 * WW;
    return (r0[x0] * wx0 + r0[x1] * wx1) * wy0 +
           (r1[x0] * wx0 + r1[x1] * wx1) * wy1;
}

__global__ void __launch_bounds__(CC)
k1_center(const float* __restrict__ img, const float* __restrict__ verts,
          const float* __restrict__ conv_w, const float* __restrict__ conv_b,
          float* __restrict__ out, float2* __restrict__ coords,
          unsigned* __restrict__ hist) {
    const int p = blockIdx.x;
    const int b = p / NN;
    const int c = threadIdx.x;
    __shared__ float s_feat[CC];
    __shared__ float s_delta[OO];
    const float vx = verts[(size_t)p * 2 + 0];
    const float vy = verts[(size_t)p * 2 + 1];
    const float* base = img + ((size_t)(b * CC + c)) * HWsz;
    const float fc = bilin_px(base, to_px_x(vx), to_px_y(vy));
    s_feat[c] = fc;
    __syncthreads();
    if (c < OO) {
        float acc = conv_b[c];
        const float* wrow = conv_w + c * CC;
        for (int k = 0; k < CC; ++k) acc += wrow[k] * s_feat[k];
        s_delta[c] = acc;
    }
    __syncthreads();
    out[(size_t)p * CC + c] = fc * (1.0f / 9.0f);
    if (c >= 1 && c < 9) {
        const float ggx = to_px_x(vx + s_delta[2 * c + 0]);
        const float ggy = to_px_y(vy + s_delta[2 * c + 1]);
        coords[p * 8 + (c - 1)] = make_float2(ggx, ggy);
        atomicAdd(&hist[((int)ggy) >> BAND_SHIFT], 1u);
    }
}

__global__ void k2_scan(const unsigned* __restrict__ hist, unsigned* __restrict__ cursor) {
    if (threadIdx.x == 0 && blockIdx.x == 0) {
        unsigned acc = 0;
        for (int i = 0; i < NB; ++i) { cursor[i] = acc; acc += hist[i]; }
    }
}

__global__ void __launch_bounds__(256)
k3_scatter(const float2* __restrict__ coords, unsigned* __restrict__ cursor,
           float* __restrict__ sgx, float* __restrict__ sgy, unsigned* __restrict__ sid) {
    const int i = blockIdx.x * 256 + threadIdx.x;
    if (i < S2) {
        const float2 cd = coords[i];
        const unsigned pos = atomicAdd(&cursor[((int)cd.y) >> BAND_SHIFT], 1u);
        sgx[pos] = cd.x; sgy[pos] = cd.y; sid[pos] = (unsigned)(i >> 3);
    }
}

__global__ void __launch_bounds__(CC)
k4_sample(const float* __restrict__ img, const float* __restrict__ sgx,
          const float* __restrict__ sgy, const unsigned* __restrict__ sid,
          float* __restrict__ out) {
    const int r = blockIdx.x;
    const int c = threadIdx.x;
    const unsigned p = sid[r];
    const int b = (p >= (unsigned)NN) ? 1 : 0;
    const float* base = img + ((size_t)(b * CC + c)) * HWsz;
    const float v = bilin_px(base, sgx[r], sgy[r]);
    atomicAdd(&out[(size_t)p * CC + c], v * (1.0f / 9.0f));
}

// ===================== Fallback #2: monolithic =====================

__global__ void __launch_bounds__(CC)
lns_kernel(const float* __restrict__ img, const float* __restrict__ verts,
           const float* __restrict__ conv_w, const float* __restrict__ conv_b,
           float* __restrict__ out) {
    const int p = blockIdx.x;
    const int b = p / NN;
    const int c = threadIdx.x;
    __shared__ float s_feat[CC];
    __shared__ float s_delta[OO];
    const float vx = verts[(size_t)p * 2 + 0];
    const float vy = verts[(size_t)p * 2 + 1];
    const float* base = img + ((size_t)(b * CC + c)) * HWsz;
    const float fc = bilin_px(base, to_px_x(vx), to_px_y(vy));
    s_feat[c] = fc;
    __syncthreads();
    if (c < OO) {
        float acc = conv_b[c];
        const float* wrow = conv_w + c * CC;
        for (int k = 0; k < CC; ++k) acc += wrow[k] * s_feat[k];
        s_delta[c] = acc;
    }
    __syncthreads();
    float acc = fc;
    for (int j = 1; j < 9; ++j)
        acc += bilin_px(base, to_px_x(vx + s_delta[2 * j]), to_px_y(vy + s_delta[2 * j + 1]));
    out[(size_t)p * CC + c] = acc * (1.0f / 9.0f);
}

extern "C" void kernel_launch(void* const* d_in, const int* in_sizes, int n_in,
                              void* d_out, int out_size, void* d_ws, size_t ws_size,
                              hipStream_t stream) {
    const float* img    = (const float*)d_in[0];
    const float* verts  = (const float*)d_in[1];
    const float* conv_w = (const float*)d_in[2];
    const float* conv_b = (const float*)d_in[3];
    float* out = (float*)d_out;

    if (ws_size >= WS_TRANS_BYTES) {
        float* trans = (float*)d_ws;
        kT<<<dim3(BB * TILES_PER_B), dim3(256), 0, stream>>>(img, trans);
        kG<<<dim3(NP), dim3(CC), 0, stream>>>(trans, verts, conv_w, conv_b, out);
        return;
    }

    if (ws_size >= WS_BAND_NEEDED) {
        char* w = (char*)d_ws;
        float2*   coords = (float2*)(w + WS_COORDS);
        float*    sgx    = (float*)(w + WS_SGX);
        float*    sgy    = (float*)(w + WS_SGY);
        unsigned* sid    = (unsigned*)(w + WS_SID);
        unsigned* hist   = (unsigned*)(w + WS_HIST);
        unsigned* cursor = (unsigned*)(w + WS_CUR);
        hipMemsetAsync(hist, 0, sizeof(unsigned) * 256, stream);
        k1_center<<<dim3(NP), dim3(CC), 0, stream>>>(img, verts, conv_w, conv_b, out, coords, hist);
        k2_scan<<<dim3(1), dim3(64), 0, stream>>>(hist, cursor);
        k3_scatter<<<dim3((S2 + 255) / 256), dim3(256), 0, stream>>>(coords, cursor, sgx, sgy, sid);
        k4_sample<<<dim3(S2), dim3(CC), 0, stream>>>(img, sgx, sgy, sid, out);
        return;
    }

    lns_kernel<<<dim3(NP), dim3(CC), 0, stream>>>(img, verts, conv_w, conv_b, out);
}